// Round 1
// baseline (439.978 us; speedup 1.0000x reference)
//
#include <hip/hip_runtime.h>

#define IN_C   256
#define OUT_C  512
#define WIDTH  56
#define HW     3136        // 56*56
#define KTOT   2304        // IN_C*9
#define NF     64
#define NU     448         // OUT_C - NF
#define NB     32
#define NGRP   8           // ic groups of 32
#define TN     64          // pixels per block (3136 = 49*64 exactly)
#define NTILE  49
#define SROWS  192         // staged slab rows (178 needed = TN + 2*57, pad to 3*64)

typedef __bf16 bf16x8 __attribute__((ext_vector_type(8)));
typedef float  f32x4  __attribute__((ext_vector_type(4)));

// ---------------- kernel 1: transpose x -> bf16 px-major, fused channel-sum partials ----
// x[b][ic][px] f32  ->  xT[b][px][ic] bf16 ;  partial[(b*49+tile)*256 + ic] = sum_px_tile x
__global__ __launch_bounds__(256) void xpose_kernel(const float* __restrict__ x,
                                                    __bf16* __restrict__ xT,
                                                    float* __restrict__ partial) {
    int id = blockIdx.x;
    int b = id / NTILE, tile = id - b * NTILE;
    int ptile = tile * TN;
    int tid = threadIdx.x;
    __shared__ float tl[64][65];     // [ic][px] tile, pad 65 -> 2-way max on both phases
    __shared__ float plsum[IN_C];
    const float* xb  = x + (size_t)b * IN_C * HW + ptile;
    __bf16*      xtb = xT + ((size_t)b * HW + ptile) * IN_C;
    int pxq  = tid & 15;     // read phase: px quad
    int rowi = tid >> 4;     // read phase: ic row within round
    int px   = tid >> 2;     // write phase: px 0..63
    int icq  = tid & 3;      // write phase: 16-ic chunk
    for (int chunk = 0; chunk < 4; ++chunk) {
        #pragma unroll
        for (int r = 0; r < 4; ++r) {
            int icL = r * 16 + rowi;
            int ic  = chunk * 64 + icL;
            float4 v = *(const float4*)(xb + (size_t)ic * HW + pxq * 4);
            *(float4*)&tl[icL][pxq * 4] = v;
            float s = v.x + v.y + v.z + v.w;        // f32 pool partial (router needs f32 accuracy)
            s += __shfl_down(s, 8, 16);
            s += __shfl_down(s, 4, 16);
            s += __shfl_down(s, 2, 16);
            s += __shfl_down(s, 1, 16);
            if (pxq == 0) plsum[ic] = s;            // each (chunk,r) hits unique ic
        }
        __syncthreads();
        bf16x8 o0, o1;
        #pragma unroll
        for (int k = 0; k < 8; ++k) o0[k] = (__bf16)tl[icq * 16 + k][px];
        #pragma unroll
        for (int k = 0; k < 8; ++k) o1[k] = (__bf16)tl[icq * 16 + 8 + k][px];
        __bf16* dst = xtb + (size_t)px * IN_C + chunk * 64 + icq * 16;
        *(bf16x8*)dst = o0;                         // 32 B/thread, fully coalesced
        *(bf16x8*)(dst + 8) = o1;
        __syncthreads();
    }
    partial[(size_t)id * IN_C + tid] = plsum[tid];
}

// ---------------- kernel 2: sel-INDEPENDENT weight fragment layout (once, all 512 oc) ----
// Wf[oc][(ic>>5)*9 + tap][ic&31] bf16  (2.36 MB, L2-resident per XCD)
__global__ __launch_bounds__(256) void wfrag_kernel(const float* __restrict__ w,
                                                    __bf16* __restrict__ wf) {
    int oc = blockIdx.x;
    const float* src = w + (size_t)oc * KTOT;
    __bf16* dst = wf + (size_t)oc * KTOT;
    int tid = threadIdx.x;
    #pragma unroll
    for (int rr = 0; rr < 9; ++rr) {
        int i = rr * 256 + tid;        // i = ic*9 + tap, coalesced read
        float v = src[i];
        int ic = i / 9, tap = i - ic * 9;
        dst[((ic >> 5) * 9 + tap) * 32 + (ic & 31)] = (__bf16)v;
    }
}

// ---------------- kernel 3: pool finalize + router GEMV + top-64 selection ----------------
__global__ __launch_bounds__(512) void router_kernel(const float* __restrict__ partial,
                                                     const float* __restrict__ rw,
                                                     const float* __restrict__ rb,
                                                     int* __restrict__ sel,
                                                     int* __restrict__ unsel) {
    int b = blockIdx.x;
    __shared__ float p[IN_C];
    __shared__ float v[OUT_C];
    __shared__ int   scount, ucount;
    int t = threadIdx.x;
    if (t < IN_C) {
        float s = 0.f;
        const float* pb = partial + (size_t)b * NTILE * IN_C + t;
        for (int k = 0; k < NTILE; ++k) s += pb[k * IN_C];   // coalesced across t
        p[t] = s * (1.0f / HW);
    }
    if (t == 0) { scount = 0; ucount = 0; }
    __syncthreads();
    float acc = rb[t];
    const float* wrow = rw + (size_t)t * IN_C;
    for (int i = 0; i < IN_C; ++i) acc += p[i] * wrow[i];
    v[t] = acc;
    __syncthreads();
    // stable rank: count strictly-greater, plus equal-with-lower-index (matches top_k tie rule)
    int cnt = 0;
    for (int j = 0; j < OUT_C; ++j) {
        float o = v[j];
        cnt += (o > acc) || (o == acc && j < t);
    }
    if (cnt < NF) {
        int pos = atomicAdd(&scount, 1);
        sel[b * NF + pos] = t;
    } else {
        int pos = atomicAdd(&ucount, 1);
        unsel[b * NU + pos] = t;
    }
}

// ---------------- kernel 4: sparse conv — 4-wave blocks, dbuf async staging -------------
// 1568 blocks (49 tiles x 32 batches, XCD-swizzled) x 256 thr. Block tile: M=64 sel-oc x N=64 px.
// Wave (mi2,s2) owns a 32-oc x 32-px quadrant: acc[2][2], af 2 loads + bfr 2 ds_reads + 4 MFMA/tap.
// Staging: 3 global_load_lds dwordx4 per wave per ic-group, double-buffered (issue g+1 under g's taps).
// LDS slot swizzle: chunk ^= (row>>1)&3 applied on global src AND ds_read (16B-granular, bijective).
__global__ __launch_bounds__(256, 4) void conv_kernel(const __bf16* __restrict__ xT,
                                                      const __bf16* __restrict__ wf,
                                                      const float* __restrict__ bias,
                                                      const int* __restrict__ sel,
                                                      const int* __restrict__ unsel,
                                                      float* __restrict__ out) {
    int id   = blockIdx.x;
    int xcd  = id & 7, slot = id >> 3;          // all 49 tiles of a batch on one XCD
    int bq   = slot / NTILE;
    int tile = slot - bq * NTILE;
    int b    = xcd * 4 + bq;
    int ptile = tile * TN;

    int tid  = threadIdx.x;
    int lane = tid & 63, w = tid >> 6;
    int fm   = lane & 15, fq = lane >> 4;
    int mi2  = w >> 1,  s2 = w & 1;

    __shared__ __bf16 xlds[2][SROWS * 32];      // 2 x 12288 B
    __shared__ int    selLds[NF];
    __shared__ int    unsLds[NU];

    size_t outb = (size_t)b * OUT_C * HW;
    const __bf16* xtb = xT + (size_t)b * HW * IN_C;

    // stage sel/unsel lists (coalesced)
    if (tid < NF) selLds[tid] = sel[b * NF + tid];
    for (int u = tid; u < NU; u += 256) unsLds[u] = unsel[b * NU + u];

    // staging source addresses (group-invariant part): row = rnd*64 + w*16 + lane/4
    const __bf16* sga[3];
    #pragma unroll
    for (int rnd = 0; rnd < 3; ++rnd) {
        int row = rnd * 64 + w * 16 + (lane >> 2);
        int cc  = (lane & 3) ^ ((row >> 1) & 3);      // inverse swizzle on source chunk
        int gp  = ptile - 57 + row;
        gp = gp < 0 ? 0 : (gp > HW - 1 ? HW - 1 : gp); // clamp; consumers mask via boundary test
        sga[rnd] = xtb + (size_t)gp * IN_C + cc * 8;
    }

#define STAGE(buf, g) { \
    _Pragma("unroll") \
    for (int rnd = 0; rnd < 3; ++rnd) \
        __builtin_amdgcn_global_load_lds( \
            (const __attribute__((address_space(1))) void*)(sga[rnd] + (g) * 32), \
            (__attribute__((address_space(3))) void*)&xlds[buf][(rnd * 64 + w * 16) * 32], \
            16, 0, 0); }

    // output px coords per local s (s = s2*2 + sl)
    int pp[2], poh[2], pow_[2];
    #pragma unroll
    for (int sl = 0; sl < 2; ++sl) {
        int p = ptile + (s2 * 2 + sl) * 16 + fm;
        pp[sl]   = p;
        poh[sl]  = p / WIDTH;
        pow_[sl] = p - poh[sl] * WIDTH;
    }

    f32x4 acc[2][2] = {};

    STAGE(0, 0);
    __syncthreads();    // drains stage-0 loads (vmcnt) + makes selLds/unsLds visible

    // zero-fill unselected planes (NT stores drain under the K-loop / across staggered blocks)
    {
        f32x4 z = {0.f, 0.f, 0.f, 0.f};
        int lq = tid & 15;
        for (int u = tid >> 4; u < NU; u += 16) {
            int oc = unsLds[u];
            __builtin_nontemporal_store(z, (f32x4*)(out + outb + (size_t)oc * HW + ptile) + lq);
        }
    }

    // A-row gather pointers (per-lane oc = selLds[mi*16 + fm])
    const __bf16* pA[2];
    #pragma unroll
    for (int m = 0; m < 2; ++m)
        pA[m] = wf + (size_t)selLds[(mi2 * 2 + m) * 16 + fm] * KTOT;

    #pragma unroll 1
    for (int g = 0; g < NGRP; ++g) {
        int cur = g & 1;
        if (g < NGRP - 1) STAGE(cur ^ 1, g + 1);   // async prefetch under this group's MFMAs
        const int gof = g * 9 * 32;
        #pragma unroll
        for (int t9 = 0; t9 < 9; ++t9) {
            const int r = t9 / 3, c = t9 - 3 * r;
            const int shift = (r - 1) * WIDTH + (c - 1);
            bf16x8 af0 = *(const bf16x8*)(pA[0] + gof + t9 * 32 + fq * 8);
            bf16x8 af1 = *(const bf16x8*)(pA[1] + gof + t9 * 32 + fq * 8);
            #pragma unroll
            for (int sl = 0; sl < 2; ++sl) {
                int row = (s2 * 2 + sl) * 16 + fm + 57 + shift;
                int ohr = poh[sl] + r - 1, owc = pow_[sl] + c - 1;
                bool ok = ((unsigned)ohr < 56u) && ((unsigned)owc < 56u);
                int sw = fq ^ ((row >> 1) & 3);                 // swizzled read slot
                bf16x8 bfr = *(const bf16x8*)&xlds[cur][row * 32 + sw * 8];
                bf16x8 zz = {};
                bfr = ok ? bfr : zz;
                acc[0][sl] = __builtin_amdgcn_mfma_f32_16x16x32_bf16(af0, bfr, acc[0][sl], 0, 0, 0);
                acc[1][sl] = __builtin_amdgcn_mfma_f32_16x16x32_bf16(af1, bfr, acc[1][sl], 0, 0, 0);
            }
        }
        __syncthreads();   // vmcnt(0): prefetched slab ready; all waves done reading cur
    }

    // epilogue: C/D layout col = lane&15 (px), row = fq*4 + reg (oc index within mi block)
    #pragma unroll
    for (int m = 0; m < 2; ++m) {
        int mi = mi2 * 2 + m;
        #pragma unroll
        for (int reg = 0; reg < 4; ++reg) {
            int oc = selLds[mi * 16 + fq * 4 + reg];
            float bs = bias[oc];
            float* orow = out + outb + (size_t)oc * HW;
            #pragma unroll
            for (int sl = 0; sl < 2; ++sl)
                __builtin_nontemporal_store(acc[m][sl][reg] + bs, &orow[pp[sl]]);
        }
    }
#undef STAGE
}

extern "C" void kernel_launch(void* const* d_in, const int* in_sizes, int n_in,
                              void* d_out, int out_size, void* d_ws, size_t ws_size,
                              hipStream_t stream) {
    (void)in_sizes; (void)n_in; (void)ws_size; (void)out_size;
    const float* x        = (const float*)d_in[0];
    const float* weight   = (const float*)d_in[1];
    const float* bias     = (const float*)d_in[2];
    const float* router_w = (const float*)d_in[3];
    const float* router_b = (const float*)d_in[4];
    float* out = (float*)d_out;

    char* ws = (char*)d_ws;
    float*  partial = (float*)ws;                    // 1568*256*4 = 1.60 MB
    int*    sel     = (int*)(ws + 0x200000);         // 8 KB
    int*    unsel   = (int*)(ws + 0x202000);         // 56 KB
    __bf16* wfb     = (__bf16*)(ws + 0x220000);      // 512*2304*2 = 2.36 MB
    __bf16* xT      = (__bf16*)(ws + 0x480000);      // 32*3136*256*2 = 51.4 MB

    xpose_kernel <<<NB * NTILE, 256, 0, stream>>>(x, xT, partial);
    wfrag_kernel <<<OUT_C,      256, 0, stream>>>(weight, wfb);
    router_kernel<<<NB,         512, 0, stream>>>(partial, router_w, router_b, sel, unsel);
    conv_kernel  <<<NTILE * NB, 256, 0, stream>>>(xT, wfb, bias, sel, unsel, out);
}

// Round 2
// 430.676 us; speedup vs baseline: 1.0216x; 1.0216x over previous
//
#include <hip/hip_runtime.h>

#define IN_C   256
#define OUT_C  512
#define WIDTH  56
#define HW     3136        // 56*56
#define KTOT   2304        // IN_C*9
#define NF     64
#define NU     448         // OUT_C - NF
#define NB     32
#define NGRP   8           // ic groups of 32
#define TN     64          // pixels per block (3136 = 49*64 exactly)
#define NTILE  49
#define SROWS  192         // staged slab rows (178 needed = TN + 2*57, pad to 3*64)

typedef __bf16 bf16x8 __attribute__((ext_vector_type(8)));
typedef float  f32x4  __attribute__((ext_vector_type(4)));

// ---------------- kernel 1: transpose x -> bf16 px-major, fused channel-sum partials ----
// x[b][ic][px] f32  ->  xT[b][px][ic] bf16 ;  partial[(b*49+tile)*256 + ic] = sum_px_tile x
__global__ __launch_bounds__(256) void xpose_kernel(const float* __restrict__ x,
                                                    __bf16* __restrict__ xT,
                                                    float* __restrict__ partial) {
    int id = blockIdx.x;
    int b = id / NTILE, tile = id - b * NTILE;
    int ptile = tile * TN;
    int tid = threadIdx.x;
    __shared__ float tl[64][65];
    __shared__ float plsum[IN_C];
    const float* xb  = x + (size_t)b * IN_C * HW + ptile;
    __bf16*      xtb = xT + ((size_t)b * HW + ptile) * IN_C;
    int pxq  = tid & 15;
    int rowi = tid >> 4;
    int px   = tid >> 2;
    int icq  = tid & 3;
    for (int chunk = 0; chunk < 4; ++chunk) {
        #pragma unroll
        for (int r = 0; r < 4; ++r) {
            int icL = r * 16 + rowi;
            int ic  = chunk * 64 + icL;
            float4 v = *(const float4*)(xb + (size_t)ic * HW + pxq * 4);
            *(float4*)&tl[icL][pxq * 4] = v;
            float s = v.x + v.y + v.z + v.w;
            s += __shfl_down(s, 8, 16);
            s += __shfl_down(s, 4, 16);
            s += __shfl_down(s, 2, 16);
            s += __shfl_down(s, 1, 16);
            if (pxq == 0) plsum[ic] = s;
        }
        __syncthreads();
        bf16x8 o0, o1;
        #pragma unroll
        for (int k = 0; k < 8; ++k) o0[k] = (__bf16)tl[icq * 16 + k][px];
        #pragma unroll
        for (int k = 0; k < 8; ++k) o1[k] = (__bf16)tl[icq * 16 + 8 + k][px];
        __bf16* dst = xtb + (size_t)px * IN_C + chunk * 64 + icq * 16;
        *(bf16x8*)dst = o0;
        *(bf16x8*)(dst + 8) = o1;
        __syncthreads();
    }
    partial[(size_t)id * IN_C + tid] = plsum[tid];
}

// ---------------- kernel 2: sel-INDEPENDENT weight fragment layout (all 512 oc) --------
// wf[oc][(ic>>5)*9 + tap][ic&31] bf16. LDS round-trip -> coalesced bf16x8 writes.
__global__ __launch_bounds__(256) void wfrag_kernel(const float* __restrict__ w,
                                                    __bf16* __restrict__ wf) {
    int oc = blockIdx.x;
    __shared__ float sm[KTOT];
    const float* src = w + (size_t)oc * KTOT;
    int tid = threadIdx.x;
    #pragma unroll
    for (int k = 0; k < 9; ++k) sm[k * 256 + tid] = src[k * 256 + tid];
    __syncthreads();
    __bf16* dst = wf + (size_t)oc * KTOT;
    for (int C = tid; C < 288; C += 256) {        // 288 chunks of 8 bf16
        int d0  = C * 8;
        int icg = d0 / 288;
        int rem = d0 - icg * 288;
        int tap = rem >> 5, icl0 = rem & 31;
        bf16x8 o;
        #pragma unroll
        for (int j = 0; j < 8; ++j)
            o[j] = (__bf16)sm[(icg * 32 + icl0 + j) * 9 + tap];
        *(bf16x8*)&dst[d0] = o;
    }
}

// ---------------- kernel 3: pool finalize + coalesced router GEMV + top-64 -------------
__global__ __launch_bounds__(512) void router_kernel(const float* __restrict__ partial,
                                                     const float* __restrict__ rw,
                                                     const float* __restrict__ rb,
                                                     int* __restrict__ sel,
                                                     int* __restrict__ unsel) {
    int b = blockIdx.x;
    __shared__ float p[IN_C];
    __shared__ float v[OUT_C];
    __shared__ int   scount, ucount;
    int t = threadIdx.x;
    if (t < IN_C) {
        float s = 0.f;
        const float* pb = partial + (size_t)b * NTILE * IN_C + t;
        for (int k = 0; k < NTILE; ++k) s += pb[k * IN_C];
        p[t] = s * (1.0f / HW);
    }
    if (t == 0) { scount = 0; ucount = 0; }
    __syncthreads();
    int w = t >> 6, lane = t & 63;
    float4 pl = *(const float4*)&p[lane * 4];      // pooled vec held in regs
    for (int k = 0; k < 64; ++k) {                 // wave w -> outputs w*64..w*64+63
        int oc = w * 64 + k;
        float4 wv = *(const float4*)&rw[(size_t)oc * IN_C + lane * 4];  // coalesced 1KB/wave
        float d = pl.x * wv.x + pl.y * wv.y + pl.z * wv.z + pl.w * wv.w;
        #pragma unroll
        for (int off = 32; off > 0; off >>= 1) d += __shfl_down(d, off, 64);
        if (lane == 0) v[oc] = d + rb[oc];
    }
    __syncthreads();
    float acc = v[t];
    int cnt = 0;
    for (int j = 0; j < OUT_C; ++j) {
        float o = v[j];
        cnt += (o > acc) || (o == acc && j < t);   // jax top_k tie rule
    }
    if (cnt < NF) {
        int pos = atomicAdd(&scount, 1);
        sel[b * NF + pos] = t;
    } else {
        int pos = atomicAdd(&ucount, 1);
        unsel[b * NU + pos] = t;
    }
}

// ---------------- kernel 4: per-batch A compaction, oc-INNER layout --------------------
// Ac[b][(g*9+tap)*2048 + oc*32 + icl] bf16: af load = contiguous 1KB per wave (L2-hot).
__global__ __launch_bounds__(256) void acomp_kernel(const __bf16* __restrict__ wf,
                                                    const int* __restrict__ sel,
                                                    __bf16* __restrict__ A) {
    int blk = blockIdx.x;
    int b = blk >> 3, part = blk & 7;
    __shared__ int s[NF];
    int tid = threadIdx.x;
    if (tid < NF) s[tid] = sel[b * NF + tid];
    __syncthreads();
    __bf16* dst = A + (size_t)b * (NF * KTOT);
    #pragma unroll
    for (int c = part * 9; c < part * 9 + 9; ++c) {
        int C = c * 256 + tid;                    // C in [0, 18432)
        int icl8 = C & 3, oc = (C >> 2) & 63, gt = C >> 8;
        bf16x8 vv = *(const bf16x8*)&wf[(size_t)s[oc] * KTOT + gt * 32 + icl8 * 8];
        *(bf16x8*)&dst[(size_t)C * 8] = vv;       // coalesced
    }
}

// ---------------- kernel 5: sparse conv — af-regs-first, dbuf async staging ------------
// 1568 blocks x 256 thr. Tile M=64 sel-oc x N=64 px. Per group: 18 af regs loaded BEFORE
// STAGE(g+1) (vmcnt in-order: taps never wait on the slab prefetch), then 9 taps of pure
// ds_read+MFMA, one barrier.
__global__ __launch_bounds__(256, 2) void conv_kernel(const __bf16* __restrict__ xT,
                                                      const __bf16* __restrict__ Ac,
                                                      const float* __restrict__ bias,
                                                      const int* __restrict__ sel,
                                                      const int* __restrict__ unsel,
                                                      float* __restrict__ out) {
    int id   = blockIdx.x;
    int xcd  = id & 7, slot = id >> 3;          // all 49 tiles of a batch on one XCD
    int bq   = slot / NTILE;
    int tile = slot - bq * NTILE;
    int b    = xcd * 4 + bq;
    int ptile = tile * TN;

    int tid  = threadIdx.x;
    int lane = tid & 63, w = tid >> 6;
    int fm   = lane & 15, fq = lane >> 4;
    int mi2  = w >> 1,  s2 = w & 1;

    __shared__ __bf16 xlds[2][SROWS * 32];      // 2 x 12288 B
    __shared__ int    selLds[NF];

    size_t outb = (size_t)b * OUT_C * HW;
    const __bf16* xtb = xT + (size_t)b * HW * IN_C;
    const __bf16* ab  = Ac + (size_t)b * (NF * KTOT);

    if (tid < NF) selLds[tid] = sel[b * NF + tid];

    // zero-fill unselected planes (direct global unsel reads; NT stores drain under K-loop)
    {
        const int* ub = unsel + b * NU;
        f32x4 z = {0.f, 0.f, 0.f, 0.f};
        int lq = tid & 15;
        for (int u = tid >> 4; u < NU; u += 16) {
            int oc = ub[u];
            __builtin_nontemporal_store(z, (f32x4*)(out + outb + (size_t)oc * HW + ptile) + lq);
        }
    }

    // staging source addresses: row = rnd*64 + w*16 + lane/4; swizzle chunk on SOURCE side
    const __bf16* sga[3];
    #pragma unroll
    for (int rnd = 0; rnd < 3; ++rnd) {
        int row = rnd * 64 + w * 16 + (lane >> 2);
        int cc  = (lane & 3) ^ ((row >> 1) & 3);
        int gp  = ptile - 57 + row;
        gp = gp < 0 ? 0 : (gp > HW - 1 ? HW - 1 : gp);
        sga[rnd] = xtb + (size_t)gp * IN_C + cc * 8;
    }

#define STAGE(buf, g) { \
    _Pragma("unroll") \
    for (int rnd = 0; rnd < 3; ++rnd) \
        __builtin_amdgcn_global_load_lds( \
            (const __attribute__((address_space(1))) void*)(sga[rnd] + (g) * 32), \
            (__attribute__((address_space(3))) void*)&xlds[buf][(rnd * 64 + w * 16) * 32], \
            16, 0, 0); }

    int pp[2], poh[2], pow_[2];
    #pragma unroll
    for (int sl = 0; sl < 2; ++sl) {
        int p = ptile + (s2 * 2 + sl) * 16 + fm;
        pp[sl]   = p;
        poh[sl]  = p / WIDTH;
        pow_[sl] = p - poh[sl] * WIDTH;
    }

    f32x4 acc[2][2] = {};

    STAGE(0, 0);
    __syncthreads();    // drains zero-fill stores + stage-0; selLds visible

    #pragma unroll 1
    for (int g = 0; g < NGRP; ++g) {
        int cur = g & 1;
        // ---- af regs for THIS group, issued before next-slab prefetch ----
        bf16x8 af[2][9];
        const __bf16* agp = ab + (size_t)(g * 9) * 2048;
        #pragma unroll
        for (int t9 = 0; t9 < 9; ++t9) {
            #pragma unroll
            for (int m = 0; m < 2; ++m)
                af[m][t9] = *(const bf16x8*)(agp + (size_t)t9 * 2048
                                             + ((mi2 * 2 + m) * 16 + fm) * 32 + fq * 8);
        }
        if (g < NGRP - 1) STAGE(cur ^ 1, g + 1);   // stays in flight through the taps
        #pragma unroll
        for (int t9 = 0; t9 < 9; ++t9) {
            const int r = t9 / 3, c = t9 - 3 * r;
            const int shift = (r - 1) * WIDTH + (c - 1);
            #pragma unroll
            for (int sl = 0; sl < 2; ++sl) {
                int row = (s2 * 2 + sl) * 16 + fm + 57 + shift;
                int ohr = poh[sl] + r - 1, owc = pow_[sl] + c - 1;
                bool ok = ((unsigned)ohr < 56u) && ((unsigned)owc < 56u);
                int sw = fq ^ ((row >> 1) & 3);
                bf16x8 bfr = *(const bf16x8*)&xlds[cur][row * 32 + sw * 8];
                bf16x8 zz = {};
                bfr = ok ? bfr : zz;
                acc[0][sl] = __builtin_amdgcn_mfma_f32_16x16x32_bf16(af[0][t9], bfr, acc[0][sl], 0, 0, 0);
                acc[1][sl] = __builtin_amdgcn_mfma_f32_16x16x32_bf16(af[1][t9], bfr, acc[1][sl], 0, 0, 0);
            }
        }
        __syncthreads();   // prefetched slab ready; all waves done reading cur
    }

    // epilogue: C/D col = lane&15 (px), row = fq*4 + reg
    #pragma unroll
    for (int m = 0; m < 2; ++m) {
        int mi = mi2 * 2 + m;
        #pragma unroll
        for (int reg = 0; reg < 4; ++reg) {
            int oc = selLds[mi * 16 + fq * 4 + reg];
            float bs = bias[oc];
            float* orow = out + outb + (size_t)oc * HW;
            #pragma unroll
            for (int sl = 0; sl < 2; ++sl)
                __builtin_nontemporal_store(acc[m][sl][reg] + bs, &orow[pp[sl]]);
        }
    }
#undef STAGE
}

extern "C" void kernel_launch(void* const* d_in, const int* in_sizes, int n_in,
                              void* d_out, int out_size, void* d_ws, size_t ws_size,
                              hipStream_t stream) {
    (void)in_sizes; (void)n_in; (void)ws_size; (void)out_size;
    const float* x        = (const float*)d_in[0];
    const float* weight   = (const float*)d_in[1];
    const float* bias     = (const float*)d_in[2];
    const float* router_w = (const float*)d_in[3];
    const float* router_b = (const float*)d_in[4];
    float* out = (float*)d_out;

    char* ws = (char*)d_ws;
    // Acomp (9.44 MB) overlaps partial (1.6 MB): partial is dead before acomp_kernel runs.
    __bf16* Acomp   = (__bf16*)ws;                     // 0x000000, 9,437,184 B
    float*  partial = (float*)ws;                      // 0x000000, 1,605,632 B (dead early)
    __bf16* wfb     = (__bf16*)(ws + 0x900000);        // 2,359,296 B
    int*    sel     = (int*)(ws + 0xB40000);           // 8 KB
    int*    unsel   = (int*)(ws + 0xB42000);           // 56 KB
    __bf16* xT      = (__bf16*)(ws + 0xB50000);        // 51,380,224 B  (total ~63.2 MB)

    xpose_kernel <<<NB * NTILE, 256, 0, stream>>>(x, xT, partial);
    wfrag_kernel <<<OUT_C,      256, 0, stream>>>(weight, wfb);
    router_kernel<<<NB,         512, 0, stream>>>(partial, router_w, router_b, sel, unsel);
    acomp_kernel <<<NB * 8,     256, 0, stream>>>(wfb, sel, Acomp);
    conv_kernel  <<<NTILE * NB, 256, 0, stream>>>(xT, Acomp, bias, sel, unsel, out);
}